// Round 2
// baseline (1038.192 us; speedup 1.0000x reference)
//
#include <hip/hip_runtime.h>
#include <stdint.h>

namespace {

constexpr int Tn = 512;
constexpr int Sn = 256;
constexpr float EPS = 1e-12f;

__launch_bounds__(256, 1)
__global__ void hmm_kernel(const float* __restrict__ emission,  // [B,T,S]
                           const float* __restrict__ weight,    // [S,S]
                           const float* __restrict__ init,      // [S]
                           float* __restrict__ out)             // [B,T,S]
{
    const int j    = threadIdx.x;   // state / output column, 0..255
    const int b    = blockIdx.x;    // batch row
    const int wave = j >> 6;
    const int lane = j & 63;

    __shared__ __align__(16) float s_m[Sn];
    __shared__ __align__(16) float s_z[Sn];
    __shared__ __align__(16) float w_buf[2][Sn];   // double-buffered w~ vector
    __shared__ __align__(16) float partial[2][4];  // wave partials of sum(w~)

    // ---- prologue 1: transition softmax row stats ----
    {
        const float* wr = weight + j * Sn;
        float m = -3.402823466e38f;
        #pragma unroll
        for (int i = 0; i < Sn; i += 4) {
            float4 v = *reinterpret_cast<const float4*>(wr + i);
            m = fmaxf(m, fmaxf(fmaxf(v.x, v.y), fmaxf(v.z, v.w)));
        }
        float z0 = 0.f, z1 = 0.f, z2 = 0.f, z3 = 0.f;
        #pragma unroll
        for (int i = 0; i < Sn; i += 4) {
            float4 v = *reinterpret_cast<const float4*>(wr + i);
            z0 += expf(v.x - m); z1 += expf(v.y - m);
            z2 += expf(v.z - m); z3 += expf(v.w - m);
        }
        s_m[j] = m;
        s_z[j] = 1.f / ((z0 + z1) + (z2 + z3));
    }
    if (j < 8) reinterpret_cast<float*>(partial)[j] = 1.0f;  // t=0 dummy l1
    __syncthreads();

    // ---- prologue 2: transition column j -> registers (const-indexed) ----
    float tc[Sn];
    #pragma unroll
    for (int k = 0; k < Sn; ++k)
        tc[k] = expf(weight[k * Sn + j] - s_m[k]) * s_z[k];
    __syncthreads();

    // ---- initial state softmax ----
    float u;
    {
        float x0 = init[j];
        float m0 = x0;
        #pragma unroll
        for (int o = 32; o >= 1; o >>= 1) m0 = fmaxf(m0, __shfl_xor(m0, o));
        if (lane == 0) s_m[wave] = m0;
        __syncthreads();
        m0 = fmaxf(fmaxf(s_m[0], s_m[1]), fmaxf(s_m[2], s_m[3]));
        float ex = expf(x0 - m0);
        float zz = ex;
        #pragma unroll
        for (int o = 32; o >= 1; o >>= 1) zz += __shfl_xor(zz, o);
        if (lane == 0) s_z[wave] = zz;
        __syncthreads();
        u = ex / ((s_z[0] + s_z[1]) + (s_z[2] + s_z[3]));
    }

    const float* em = emission + (size_t)b * Tn * Sn + j;
    float*       op = out      + (size_t)b * Tn * Sn + j;

    float wreg  = u * em[0];   // w~_0 (unnormalized from here on)
    float enext = em[Sn];      // e_1
    w_buf[0][j] = wreg;
    float acc_prev = 0.f;

// 8 FMAs against one float4-pair of the broadcast w vector
#define FMA8(q) {                                                   \
        float4 v0 = w4[2 * (q)];                                    \
        float4 v1 = w4[2 * (q) + 1];                                \
        a0 = fmaf(v0.x, tc[8 * (q) + 0], a0);                       \
        a1 = fmaf(v0.y, tc[8 * (q) + 1], a1);                       \
        a2 = fmaf(v0.z, tc[8 * (q) + 2], a2);                       \
        a3 = fmaf(v0.w, tc[8 * (q) + 3], a3);                       \
        a4 = fmaf(v1.x, tc[8 * (q) + 4], a4);                       \
        a5 = fmaf(v1.y, tc[8 * (q) + 5], a5);                       \
        a6 = fmaf(v1.z, tc[8 * (q) + 6], a6);                       \
        a7 = fmaf(v1.w, tc[8 * (q) + 7], a7);                       \
    }
#define FMA32(Q) FMA8(Q) FMA8((Q)+1) FMA8((Q)+2) FMA8((Q)+3)

    for (int t = 0; t < Tn; ++t) {
        __syncthreads();                 // w~_t visible in w_buf[p]
        const int p = t & 1;

        // prefetch e_{t+2} (global, hidden under the FMA loop)
        const int tp = (t + 2 < Tn) ? (t + 2) : (Tn - 1);
        const float e2 = em[(size_t)tp * Sn];

        // issue read of previous step's partials FIRST (in-order LDS
        // returns: its wait is subsumed by the first w-read's wait)
        const float4 pp = *reinterpret_cast<const float4*>(partial[p ^ 1]);

        const float4* w4 = reinterpret_cast<const float4*>(w_buf[p]);
        float a0 = 0.f, a1 = 0.f, a2 = 0.f, a3 = 0.f;
        float a4 = 0.f, a5 = 0.f, a6 = 0.f, a7 = 0.f;
        float r = wreg;                  // wave L1 reduce, interleaved below

        FMA32(0)   r += __shfl_xor(r, 32);
        FMA32(4)   r += __shfl_xor(r, 16);
        FMA32(8)   r += __shfl_xor(r, 8);
        FMA32(12)  r += __shfl_xor(r, 4);
        FMA32(16)  r += __shfl_xor(r, 2);
        FMA32(20)  r += __shfl_xor(r, 1);
        FMA32(24)  if (lane == 0) partial[p][wave] = r;
        FMA32(28)

        // finish step t-1 (off critical path): l1 -> inv -> out store
        float l1  = fmaxf((pp.x + pp.y) + (pp.z + pp.w), EPS);
        float inv = 1.f / l1;
        const int ts = (t == 0) ? 0 : (t - 1);   // t=0 writes dummy, fixed at t=1
        op[(size_t)ts * Sn] = acc_prev * inv;

        // exact power-of-2 rescale (no rounding error, keeps magnitude sane)
        uint32_t ebits = __float_as_uint(l1) & 0x7f800000u;
        float sigma = __uint_as_float(0x7f000000u - ebits);

        float acc = ((a0 + a1) + (a2 + a3)) + ((a4 + a5) + (a6 + a7));
        acc_prev = acc;
        wreg = (acc * sigma) * enext;    // w~_{t+1}
        enext = e2;
        w_buf[p ^ 1][j] = wreg;
    }

    // epilogue: out_{T-1}
    __syncthreads();
    {
        const float4 pp = *reinterpret_cast<const float4*>(partial[(Tn - 1) & 1]);
        float l1  = fmaxf((pp.x + pp.y) + (pp.z + pp.w), EPS);
        op[(size_t)(Tn - 1) * Sn] = acc_prev * (1.f / l1);
    }

#undef FMA8
#undef FMA32
}

} // namespace

extern "C" void kernel_launch(void* const* d_in, const int* in_sizes, int n_in,
                              void* d_out, int out_size, void* d_ws, size_t ws_size,
                              hipStream_t stream) {
    const float* emission = (const float*)d_in[0];
    const float* weight   = (const float*)d_in[1];
    const float* init     = (const float*)d_in[2];
    float* outp = (float*)d_out;
    const int Bn = in_sizes[0] / (Tn * Sn);   // 128 for the reference shapes

    hipLaunchKernelGGL(hmm_kernel, dim3(Bn), dim3(256), 0, stream,
                       emission, weight, init, outp);
}